// Round 9
// baseline (265.579 us; speedup 1.0000x reference)
//
#include <hip/hip_runtime.h>
#include <math.h>

#define HID 64
#define HEADS 8
#define NUM_LAYERS 3

typedef __attribute__((ext_vector_type(8))) short bf16x8;
typedef __attribute__((ext_vector_type(4))) float f32x4;

// ---------------------------------------------------------------------------
// bf16 helpers (storage compression; accumulation stays f32)
// ---------------------------------------------------------------------------
__device__ __forceinline__ unsigned short f2bf(float f) {
    union { float f; unsigned int u; } cv; cv.f = f;
    unsigned int u = cv.u;
    unsigned int r = (u + 0x7FFFu + ((u >> 16) & 1u)) >> 16;  // RNE
    return (unsigned short)r;
}
__device__ __forceinline__ float bflo(unsigned int u) {
    union { unsigned int u; float f; } cv; cv.u = u << 16; return cv.f;
}
__device__ __forceinline__ float bfhi(unsigned int u) {
    union { unsigned int u; float f; } cv; cv.u = u & 0xFFFF0000u; return cv.f;
}
__device__ __forceinline__ unsigned relu_pk(unsigned u) {  // relu on 2 packed bf16
    unsigned m = ((u & 0x8000u) ? 0u : 0xFFFFu) |
                 ((u & 0x80000000u) ? 0u : 0xFFFF0000u);
    return u & m;
}

// ---------------------------------------------------------------------------
// MFMA GEMM core: block = 64 nodes x 64 oc, 4 waves, wave w = 16-row strip.
// A in LDS row-major bf16 (stride 72); W in LDS transposed bf16 [n][k].
// A-frag: A[m=lane&15][k=quad*8+j]; C/D: col=lane&15, row=quad*4+reg.
// ---------------------------------------------------------------------------
#define ALD 72

__device__ __forceinline__ void stage_w_bf16(unsigned short* Wt,
                                             const float* __restrict__ w, int tid) {
    for (int idx = tid; idx < 1024; idx += 256) {
        int k = idx >> 4, n4 = (idx & 15) * 4;
        float4 wv = *(const float4*)&w[k * 64 + n4];
        Wt[(n4 + 0) * ALD + k] = f2bf(wv.x);
        Wt[(n4 + 1) * ALD + k] = f2bf(wv.y);
        Wt[(n4 + 2) * ALD + k] = f2bf(wv.z);
        Wt[(n4 + 3) * ALD + k] = f2bf(wv.w);
    }
}

__device__ __forceinline__ void mfma_step(const unsigned short* Alds,
                                          const unsigned short* Wt,
                                          int tid, f32x4 acc[4]) {
    int lane = tid & 63;
    int m0 = (tid >> 6) * 16;
    int c16 = lane & 15, quad = lane >> 4;
    const unsigned short* ar = &Alds[(m0 + c16) * ALD + quad * 8];
    bf16x8 a0 = *(const bf16x8*)ar;
    bf16x8 a1 = *(const bf16x8*)(ar + 32);
#pragma unroll
    for (int nt = 0; nt < 4; ++nt) {
        const unsigned short* br = &Wt[(nt * 16 + c16) * ALD + quad * 8];
        bf16x8 b0 = *(const bf16x8*)br;
        bf16x8 b1 = *(const bf16x8*)(br + 32);
        acc[nt] = __builtin_amdgcn_mfma_f32_16x16x32_bf16(a0, b0, acc[nt], 0, 0, 0);
        acc[nt] = __builtin_amdgcn_mfma_f32_16x16x32_bf16(a1, b1, acc[nt], 0, 0, 0);
    }
}

// ---------------------------------------------------------------------------
// Fused: lin1 (+ layer-0 V GEMM) on grid.y==0, degree count on grid.y==1.
// ---------------------------------------------------------------------------
__global__ __launch_bounds__(256, 4) void k_lin1c(
    const float* __restrict__ x, const float* __restrict__ w,
    const float* __restrict__ b, const float* __restrict__ wv0,
    const float* __restrict__ bv0, unsigned short* __restrict__ h,
    unsigned short* __restrict__ kv, int n,
    const int* __restrict__ col, int* __restrict__ counts, int E, int gx) {
    __shared__ __align__(16) unsigned short Alds[64 * ALD];
    __shared__ __align__(16) unsigned short Wt[64 * ALD];
    int tid = threadIdx.x;
    if (blockIdx.y == 1) {  // degree count
        int stride = gx * 256;
        for (int e = blockIdx.x * 256 + tid; e < E; e += stride)
            atomicAdd(&counts[col[e]], 1);
        return;
    }
    int node0 = blockIdx.x * 64;
    f32x4 acc[4];
#pragma unroll
    for (int nt = 0; nt < 4; ++nt) acc[nt] = (f32x4){0.f, 0.f, 0.f, 0.f};

    for (int kc = 0; kc < 256; kc += 64) {
        __syncthreads();
        stage_w_bf16(Wt, w + kc * 64, tid);
        for (int idx = tid; idx < 1024; idx += 256) {
            int r = idx >> 4, c4 = (idx & 15) * 4;
            int node = node0 + r;
            float4 v = make_float4(0.f, 0.f, 0.f, 0.f);
            if (node < n) v = *(const float4*)&x[(size_t)node * 256 + kc + c4];
            Alds[r * ALD + c4 + 0] = f2bf(v.x);
            Alds[r * ALD + c4 + 1] = f2bf(v.y);
            Alds[r * ALD + c4 + 2] = f2bf(v.z);
            Alds[r * ALD + c4 + 3] = f2bf(v.w);
        }
        __syncthreads();
        mfma_step(Alds, Wt, tid, acc);
    }
    int lane = tid & 63;
    int m0 = (tid >> 6) * 16, c16 = lane & 15, quad = lane >> 4;
    float bias[4];
#pragma unroll
    for (int nt = 0; nt < 4; ++nt) bias[nt] = b[nt * 16 + c16];

    __syncthreads();
    stage_w_bf16(Wt, wv0, tid);
#pragma unroll
    for (int i = 0; i < 4; ++i) {
        int row = m0 + quad * 4 + i;
        int node = node0 + row;
#pragma unroll
        for (int nt = 0; nt < 4; ++nt) {
            unsigned short hb = f2bf(fmaxf(acc[nt][i] + bias[nt], 0.f));
            Alds[row * ALD + nt * 16 + c16] = hb;
            if (node < n) h[(size_t)node * 64 + nt * 16 + c16] = hb;
        }
    }
    __syncthreads();
    f32x4 acc2[4];
#pragma unroll
    for (int nt = 0; nt < 4; ++nt) acc2[nt] = (f32x4){0.f, 0.f, 0.f, 0.f};
    mfma_step(Alds, Wt, tid, acc2);
    float bias2[4];
#pragma unroll
    for (int nt = 0; nt < 4; ++nt) bias2[nt] = bv0[nt * 16 + c16];
#pragma unroll
    for (int i = 0; i < 4; ++i) {
        int node = node0 + m0 + quad * 4 + i;
        if (node < n) {
#pragma unroll
            for (int nt = 0; nt < 4; ++nt)
                kv[(size_t)node * 64 + nt * 16 + c16] = f2bf(acc2[nt][i] + bias2[nt]);
        }
    }
}

// ---------------------------------------------------------------------------
// Single-block scan: thread-chunked single pass (counts left intact).
// ---------------------------------------------------------------------------
__global__ __launch_bounds__(1024) void k_scan(const int* __restrict__ counts,
                                               int* __restrict__ start,
                                               float* __restrict__ dinv, int n) {
    __shared__ int wsum[16];
    int tid = threadIdx.x;
    int lane = tid & 63, wv = tid >> 6;
    int ipt = (n + 1023) >> 10;
    int c0 = tid * ipt;
    int c1 = min(n, c0 + ipt);
    int s = 0;
    for (int i = c0; i < c1; ++i) s += counts[i];
    int x = s;
#pragma unroll
    for (int off = 1; off < 64; off <<= 1) {
        int y = __shfl_up(x, off);
        if (lane >= off) x += y;
    }
    if (lane == 63) wsum[wv] = x;
    __syncthreads();
    if (wv == 0 && lane < 16) {
        int t2 = wsum[lane];
#pragma unroll
        for (int off = 1; off < 16; off <<= 1) {
            int y = __shfl_up(t2, off);
            if (lane >= off) t2 += y;
        }
        wsum[lane] = t2;
    }
    __syncthreads();
    int waveoff = (wv > 0) ? wsum[wv - 1] : 0;
    int run = waveoff + x - s;
    for (int i = c0; i < c1; ++i) {
        int v = counts[i];
        start[i] = run;
        dinv[i] = rsqrtf((float)(v + 1));  // +1 self-loop
        run += v;
    }
    if (tid == 0) start[n] = wsum[15];
}

// scatter: reuse counts as the fill cursor (atomicSub -> slots count-1..0)
__global__ void k_scatter(const int* __restrict__ ei, const int* __restrict__ start,
                          int* __restrict__ counts, int* __restrict__ ebuf, int E) {
    int e = blockIdx.x * blockDim.x + threadIdx.x;
    if (e >= E) return;
    int r = ei[e], c = ei[E + e];
    int pos = start[c] + atomicSub(&counts[c], 1) - 1;
    ebuf[pos] = r;
}

// ---------------------------------------------------------------------------
// batched 64x64 MFMA GEMM for q / K / V of one layer (layers 1..2).
// job: 0 -> q (bf16), 1..t -> K slice s, t+1..2t -> V slice s (bf16 kv).
// kv layout [node][s][K64|V64], stride t*128.
// ---------------------------------------------------------------------------
__global__ __launch_bounds__(256, 4) void k_qkv(
    const unsigned short* __restrict__ xsbase,
    const float* __restrict__ wq, const float* __restrict__ bq,
    const float* __restrict__ wk, const float* __restrict__ bk,
    const float* __restrict__ wv, const float* __restrict__ bv,
    unsigned short* __restrict__ q, unsigned short* __restrict__ kv,
    int n, int layer, int t, int kv_stride) {
    int job = blockIdx.y;
    const unsigned short* src; const float* w; const float* b; bool relu_in;
    unsigned short* dst; size_t dstride; int dst_off;
    if (job == 0) {
        src = xsbase + (size_t)layer * n * 64;
        w = wq + layer * 4096; b = bq + layer * 64;
        relu_in = (layer >= 1);
        dst = q; dstride = 64; dst_off = 0;
    } else if (job <= t) {
        int s = job - 1;
        src = xsbase + (size_t)s * n * 64;
        w = wk + layer * 4096; b = bk + layer * 64;
        relu_in = (s >= 1);
        dst = kv; dstride = kv_stride; dst_off = s * 128;
    } else {
        int s = job - t - 1;
        src = xsbase + (size_t)s * n * 64;
        w = wv + layer * 4096; b = bv + layer * 64;
        relu_in = (s >= 1);
        dst = kv; dstride = kv_stride; dst_off = s * 128 + 64;
    }
    __shared__ __align__(16) unsigned short Alds[64 * ALD];
    __shared__ __align__(16) unsigned short Wt[64 * ALD];
    int tid = threadIdx.x;
    int node0 = blockIdx.x * 64;
    stage_w_bf16(Wt, w, tid);
    for (int idx = tid; idx < 512; idx += 256) {
        int r = idx >> 3, seg = idx & 7;
        int node = node0 + r;
        uint4 u = make_uint4(0u, 0u, 0u, 0u);
        if (node < n) u = *(const uint4*)&src[(size_t)node * 64 + seg * 8];
        if (relu_in) {
            u.x = relu_pk(u.x); u.y = relu_pk(u.y);
            u.z = relu_pk(u.z); u.w = relu_pk(u.w);
        }
        *(uint4*)&Alds[r * ALD + seg * 8] = u;
    }
    __syncthreads();
    f32x4 acc[4];
#pragma unroll
    for (int nt = 0; nt < 4; ++nt) acc[nt] = (f32x4){0.f, 0.f, 0.f, 0.f};
    mfma_step(Alds, Wt, tid, acc);

    int lane = tid & 63;
    int m0 = (tid >> 6) * 16, c16 = lane & 15, quad = lane >> 4;
    float bias[4];
#pragma unroll
    for (int nt = 0; nt < 4; ++nt) bias[nt] = b[nt * 16 + c16];
#pragma unroll
    for (int i = 0; i < 4; ++i) {
        int node = node0 + m0 + quad * 4 + i;
        if (node < n) {
#pragma unroll
            for (int nt = 0; nt < 4; ++nt)
                dst[(size_t)node * dstride + dst_off + nt * 16 + c16] =
                    f2bf(acc[nt][i] + bias[nt]);
        }
    }
}

// ---------------------------------------------------------------------------
// attention + aggregate, CSR by destination.  One wave per node.
// Lane = (edge-slot g = lane>>3, head h = lane&7): 8 edges in flight.
// Neighbor ids + dinv preloaded into registers; iterations get r via __shfl.
// T==1: softmax == 1 -> pure dinv-weighted V gather (kv stride 64).
// ---------------------------------------------------------------------------
template <int T>
__global__ __launch_bounds__(256) void k_attn_g(
    const int* __restrict__ start, const int* __restrict__ ebuf,
    const float* __restrict__ dinv, const unsigned short* __restrict__ qb,
    const unsigned short* __restrict__ kv, unsigned short* __restrict__ outp, int n) {
    const int KVS = (T == 1) ? 64 : T * 128;
    int node = (int)((blockIdx.x * (size_t)blockDim.x + threadIdx.x) >> 6);
    int lane = threadIdx.x & 63;
    if (node >= n) return;
    int g = lane >> 3;
    int cb = (lane & 7) * 8;
    const float isd = 0.35355339059327373f;  // 1/sqrt(8)

    float qv[8];
    if (T > 1) {
        uint4 qu = *(const uint4*)&qb[(size_t)node * 64 + cb];
        qv[0] = bflo(qu.x); qv[1] = bfhi(qu.x);
        qv[2] = bflo(qu.y); qv[3] = bfhi(qu.y);
        qv[4] = bflo(qu.z); qv[5] = bfhi(qu.z);
        qv[6] = bflo(qu.w); qv[7] = bfhi(qu.w);
    }
    float dc = dinv[node];
    int s0 = start[node];
    int cnt = start[node + 1] - s0 + 1;  // + self-loop (slot 0)

    // preload neighbor ids + dinv (slot 0 = self)
    int rp = node;
    if (lane >= 1 && lane < cnt) rp = ebuf[s0 + lane - 1];
    float dp = dinv[rp];

    float acc[8];
#pragma unroll
    for (int k = 0; k < 8; ++k) acc[k] = 0.f;

    for (int base = 0; base < cnt; base += 8) {
        int idx = base + g;
        bool valid = idx < cnt;
        int r = __shfl(rp, idx & 63);
        float dr = __shfl(dp, idx & 63);
        if (idx >= 64 && valid) { r = ebuf[s0 + idx - 1]; dr = dinv[r]; }
        if (!valid) dr = 0.f;
        const unsigned short* rkv = kv + (size_t)r * KVS;

        float sc[T];
        float wgt;
        if (T > 1) {
            float m = -1e30f;
#pragma unroll
            for (int s = 0; s < T; ++s) {
                uint4 ku = *(const uint4*)&rkv[s * 128 + cb];
                float p = qv[0] * bflo(ku.x) + qv[1] * bfhi(ku.x)
                        + qv[2] * bflo(ku.y) + qv[3] * bfhi(ku.y)
                        + qv[4] * bflo(ku.z) + qv[5] * bfhi(ku.z)
                        + qv[6] * bflo(ku.w) + qv[7] * bfhi(ku.w);
                p *= isd;
                sc[s] = p;
                m = fmaxf(m, p);
            }
            float denom = 0.f;
#pragma unroll
            for (int s = 0; s < T; ++s) { sc[s] = __expf(sc[s] - m); denom += sc[s]; }
            wgt = dr / denom;
        } else {
            sc[0] = 1.f;
            wgt = dr;
        }

        float mg[8];
#pragma unroll
        for (int k = 0; k < 8; ++k) mg[k] = 0.f;
#pragma unroll
        for (int s = 0; s < T; ++s) {
            uint4 vu = *(const uint4*)&rkv[((T == 1) ? 0 : s * 128 + 64) + cb];
            float wv_ = sc[s];
            mg[0] += wv_ * bflo(vu.x); mg[1] += wv_ * bfhi(vu.x);
            mg[2] += wv_ * bflo(vu.y); mg[3] += wv_ * bfhi(vu.y);
            mg[4] += wv_ * bflo(vu.z); mg[5] += wv_ * bfhi(vu.z);
            mg[6] += wv_ * bflo(vu.w); mg[7] += wv_ * bfhi(vu.w);
        }
#pragma unroll
        for (int k = 0; k < 8; ++k) acc[k] += wgt * mg[k];
    }

#pragma unroll
    for (int off = 8; off < 64; off <<= 1) {
#pragma unroll
        for (int k = 0; k < 8; ++k) acc[k] += __shfl_xor(acc[k], off);
    }
    if (g == 0) {
        ushort4 o0, o1;
        o0.x = f2bf(acc[0] * dc); o0.y = f2bf(acc[1] * dc);
        o0.z = f2bf(acc[2] * dc); o0.w = f2bf(acc[3] * dc);
        o1.x = f2bf(acc[4] * dc); o1.y = f2bf(acc[5] * dc);
        o1.z = f2bf(acc[6] * dc); o1.w = f2bf(acc[7] * dc);
        *(ushort4*)&outp[(size_t)node * 64 + cb] = o0;
        *(ushort4*)&outp[(size_t)node * 64 + cb + 4] = o1;
    }
}

// ---------------------------------------------------------------------------
// layer-2 attention fused with final projection + log_softmax.
// ---------------------------------------------------------------------------
__global__ __launch_bounds__(256) void k_attn3f(
    const int* __restrict__ start, const int* __restrict__ ebuf,
    const float* __restrict__ dinv, const unsigned short* __restrict__ qb,
    const unsigned short* __restrict__ kv,
    const float* __restrict__ w2, const float* __restrict__ b2,
    float* __restrict__ outp, int n) {
    const int T = 3, KVS = 384;
    int node = (int)((blockIdx.x * (size_t)blockDim.x + threadIdx.x) >> 6);
    int lane = threadIdx.x & 63;
    if (node >= n) return;
    int g = lane >> 3;
    int cb = (lane & 7) * 8;
    const float isd = 0.35355339059327373f;

    float qv[8];
    {
        uint4 qu = *(const uint4*)&qb[(size_t)node * 64 + cb];
        qv[0] = bflo(qu.x); qv[1] = bfhi(qu.x);
        qv[2] = bflo(qu.y); qv[3] = bfhi(qu.y);
        qv[4] = bflo(qu.z); qv[5] = bfhi(qu.z);
        qv[6] = bflo(qu.w); qv[7] = bfhi(qu.w);
    }
    float dc = dinv[node];
    int s0 = start[node];
    int cnt = start[node + 1] - s0 + 1;

    int rp = node;
    if (lane >= 1 && lane < cnt) rp = ebuf[s0 + lane - 1];
    float dp = dinv[rp];

    float acc[8];
#pragma unroll
    for (int k = 0; k < 8; ++k) acc[k] = 0.f;

    for (int base = 0; base < cnt; base += 8) {
        int idx = base + g;
        bool valid = idx < cnt;
        int r = __shfl(rp, idx & 63);
        float dr = __shfl(dp, idx & 63);
        if (idx >= 64 && valid) { r = ebuf[s0 + idx - 1]; dr = dinv[r]; }
        if (!valid) dr = 0.f;
        const unsigned short* rkv = kv + (size_t)r * KVS;

        float sc[T];
        float m = -1e30f;
#pragma unroll
        for (int s = 0; s < T; ++s) {
            uint4 ku = *(const uint4*)&rkv[s * 128 + cb];
            float p = qv[0] * bflo(ku.x) + qv[1] * bfhi(ku.x)
                    + qv[2] * bflo(ku.y) + qv[3] * bfhi(ku.y)
                    + qv[4] * bflo(ku.z) + qv[5] * bfhi(ku.z)
                    + qv[6] * bflo(ku.w) + qv[7] * bfhi(ku.w);
            p *= isd;
            sc[s] = p;
            m = fmaxf(m, p);
        }
        float denom = 0.f;
#pragma unroll
        for (int s = 0; s < T; ++s) { sc[s] = __expf(sc[s] - m); denom += sc[s]; }
        float wgt = dr / denom;

        float mg[8];
#pragma unroll
        for (int k = 0; k < 8; ++k) mg[k] = 0.f;
#pragma unroll
        for (int s = 0; s < T; ++s) {
            uint4 vu = *(const uint4*)&rkv[s * 128 + 64 + cb];
            float wv_ = sc[s];
            mg[0] += wv_ * bflo(vu.x); mg[1] += wv_ * bfhi(vu.x);
            mg[2] += wv_ * bflo(vu.y); mg[3] += wv_ * bfhi(vu.y);
            mg[4] += wv_ * bflo(vu.z); mg[5] += wv_ * bfhi(vu.z);
            mg[6] += wv_ * bflo(vu.w); mg[7] += wv_ * bfhi(vu.w);
        }
#pragma unroll
        for (int k = 0; k < 8; ++k) acc[k] += wgt * mg[k];
    }

#pragma unroll
    for (int off = 8; off < 64; off <<= 1) {
#pragma unroll
        for (int k = 0; k < 8; ++k) acc[k] += __shfl_xor(acc[k], off);
    }
    // channel c lives in lane (c>>3), register acc[c&7]
    float lg = b2[lane];
#pragma unroll
    for (int c = 0; c < 64; ++c) {
        float xc = fmaxf(__shfl(acc[c & 7], c >> 3) * dc, 0.f);
        lg += xc * w2[c * 64 + lane];
    }
    float mx = lg;
#pragma unroll
    for (int off = 1; off < 64; off <<= 1) mx = fmaxf(mx, __shfl_xor(mx, off));
    float e = __expf(lg - mx);
    float ssum = e;
#pragma unroll
    for (int off = 1; off < 64; off <<= 1) ssum += __shfl_xor(ssum, off);
    outp[(size_t)node * 64 + lane] = lg - mx - __logf(ssum);
}

// ---------------------------------------------------------------------------
extern "C" void kernel_launch(void* const* d_in, const int* in_sizes, int n_in,
                              void* d_out, int out_size, void* d_ws, size_t ws_size,
                              hipStream_t stream) {
    const float* x  = (const float*)d_in[0];
    const int*   ei = (const int*)d_in[1];
    const float* w1 = (const float*)d_in[2];
    const float* b1 = (const float*)d_in[3];
    const float* wq = (const float*)d_in[4];
    const float* bq = (const float*)d_in[5];
    const float* wk = (const float*)d_in[6];
    const float* bk = (const float*)d_in[7];
    const float* wv = (const float*)d_in[8];
    const float* bv = (const float*)d_in[9];
    const float* w2 = (const float*)d_in[10];
    const float* b2 = (const float*)d_in[11];
    float* outp = (float*)d_out;

    int n = in_sizes[0] / 256;
    int E = in_sizes[1] / 2;

    // workspace layout (offsets in FLOAT units; sizes annotated in both units)
    float* ws = (float*)d_ws;
    size_t off = 0;
    float* dinv = ws + off; off += (size_t)n;                                   // n f32
    unsigned short* qb  = (unsigned short*)(ws + off); off += (size_t)n * 32;   // n*64  bf16 = n*32  f32
    unsigned short* xsU = (unsigned short*)(ws + off); off += (size_t)n * 96;   // n*192 bf16 = n*96  f32 (3 slices)
    unsigned short* kvU = (unsigned short*)(ws + off); off += (size_t)n * 192;  // n*384 bf16 = n*192 f32
    int* wsI    = (int*)(ws + off);
    int* counts = wsI;                 // n (doubles as scatter cursor)
    int* startA = wsI + n;             // n+1
    int* ebuf   = wsI + 2 * n + 1;     // E

    int gx = (n + 63) / 64;

    // zero counts; fused lin1+V0+count; scan; scatter
    hipMemsetAsync(counts, 0, (size_t)n * sizeof(int), stream);
    {
        dim3 grid(gx, 2);
        k_lin1c<<<grid, 256, 0, stream>>>(x, w1, b1, wv, bv, xsU, kvU, n,
                                          ei + E, counts, E, gx);
    }
    k_scan<<<1, 1024, 0, stream>>>(counts, startA, dinv, n);
    k_scatter<<<(E + 255) / 256, 256, 0, stream>>>(ei, startA, counts, ebuf, E);

    int attn_grid = (int)(((size_t)n * 64 + 255) / 256);

    // layer 0 attention (T=1)
    k_attn_g<1><<<attn_grid, 256, 0, stream>>>(startA, ebuf, dinv, qb, kvU,
                                               xsU + (size_t)n * 64, n);
    // layer 1
    {
        dim3 grid(gx, 5);
        k_qkv<<<grid, 256, 0, stream>>>(xsU, wq, bq, wk, bk, wv, bv,
                                        qb, kvU, n, 1, 2, 256);
        k_attn_g<2><<<attn_grid, 256, 0, stream>>>(startA, ebuf, dinv, qb, kvU,
                                                   xsU + (size_t)n * 128, n);
    }
    // layer 2 + fused final
    {
        dim3 grid(gx, 7);
        k_qkv<<<grid, 256, 0, stream>>>(xsU, wq, bq, wk, bk, wv, bv,
                                        qb, kvU, n, 2, 3, 384);
        k_attn3f<<<attn_grid, 256, 0, stream>>>(startA, ebuf, dinv, qb, kvU,
                                                w2, b2, outp, n);
    }
}